// Round 1
// baseline (1562.794 us; speedup 1.0000x reference)
//
#include <hip/hip_runtime.h>
#include <cstdint>
#include <cstddef>

#define N_ROWS   65536
#define D_IN     512
#define D_OUT    512
#define N_WORDS  256
#define N_BOOKS  8
#define L_WORD   64
#define TAU      5.0f

// ---------------- Kernel 1: X = x @ W^T + b  (fp32 SGEMM, NT layout) ----------------
#define BM 128
#define BN 128
#define BK 16
#define PAD_AB 4

__global__ __launch_bounds__(256) void gemm_fc(
        const float* __restrict__ x, const float* __restrict__ W,
        const float* __restrict__ b, float* __restrict__ X) {
    __shared__ float As[BK][BM + PAD_AB];
    __shared__ float Bs[BK][BN + PAD_AB];

    const int tid = threadIdx.x;
    const int bm  = blockIdx.x >> 2;   // 512 row tiles
    const int bn  = blockIdx.x & 3;    // 4 col tiles
    const int n0  = bm * BM;
    const int c0  = bn * BN;
    const int tx  = tid & 15;
    const int ty  = tid >> 4;

    float acc[8][8] = {};

    for (int k0 = 0; k0 < D_IN; k0 += BK) {
        // stage A (x rows) and B (W rows) tiles, transposed into [k][m] layout
        #pragma unroll
        for (int i = 0; i < 2; ++i) {
            const int s   = tid + 256 * i;     // 0..511
            const int row = s >> 2;            // 0..127
            const int kq  = (s & 3) << 2;      // 0,4,8,12
            const float4 va = *reinterpret_cast<const float4*>(
                &x[(size_t)(n0 + row) * D_IN + k0 + kq]);
            As[kq + 0][row] = va.x; As[kq + 1][row] = va.y;
            As[kq + 2][row] = va.z; As[kq + 3][row] = va.w;
            const float4 vb = *reinterpret_cast<const float4*>(
                &W[(size_t)(c0 + row) * D_IN + k0 + kq]);
            Bs[kq + 0][row] = vb.x; Bs[kq + 1][row] = vb.y;
            Bs[kq + 2][row] = vb.z; Bs[kq + 3][row] = vb.w;
        }
        __syncthreads();
        #pragma unroll
        for (int kk = 0; kk < BK; ++kk) {
            float a[8], bb[8];
            *reinterpret_cast<float4*>(&a[0])  = *reinterpret_cast<const float4*>(&As[kk][ty * 8]);
            *reinterpret_cast<float4*>(&a[4])  = *reinterpret_cast<const float4*>(&As[kk][ty * 8 + 4]);
            *reinterpret_cast<float4*>(&bb[0]) = *reinterpret_cast<const float4*>(&Bs[kk][tx * 8]);
            *reinterpret_cast<float4*>(&bb[4]) = *reinterpret_cast<const float4*>(&Bs[kk][tx * 8 + 4]);
            #pragma unroll
            for (int i = 0; i < 8; ++i)
                #pragma unroll
                for (int j = 0; j < 8; ++j)
                    acc[i][j] = fmaf(a[i], bb[j], acc[i][j]);
        }
        __syncthreads();
    }

    float bias[8];
    #pragma unroll
    for (int j = 0; j < 8; ++j) bias[j] = b[c0 + tx * 8 + j];
    #pragma unroll
    for (int i = 0; i < 8; ++i) {
        const size_t off = (size_t)(n0 + ty * 8 + i) * D_OUT + c0 + tx * 8;
        float4 o;
        o.x = acc[i][0] + bias[0]; o.y = acc[i][1] + bias[1];
        o.z = acc[i][2] + bias[2]; o.w = acc[i][3] + bias[3];
        *reinterpret_cast<float4*>(&X[off]) = o;
        o.x = acc[i][4] + bias[4]; o.y = acc[i][5] + bias[5];
        o.z = acc[i][6] + bias[6]; o.w = acc[i][7] + bias[7];
        *reinterpret_cast<float4*>(&X[off + 4]) = o;
    }
}

// ---------------- Kernel 2: per-book soft quantization ----------------
// One block = (book, 32 rows). LDS: Cb[256][68], Xs[32][68], dist[32][256], c2, x2.
#define ROWS 32
#define PC   68   // padded leading dim (float4-aligned, breaks bank patterns)

__global__ __launch_bounds__(256) void quant_head(
        const float* __restrict__ X, const float* __restrict__ C,
        float* __restrict__ Z) {
    extern __shared__ float smem[];
    float (*Cb)[PC]       = reinterpret_cast<float(*)[PC]>(smem);                       // 256x68
    float (*Xs)[PC]       = reinterpret_cast<float(*)[PC]>(smem + N_WORDS * PC);        // 32x68
    float (*dist)[N_WORDS]= reinterpret_cast<float(*)[N_WORDS]>(smem + (N_WORDS + ROWS) * PC); // 32x256
    float* c2 = smem + (N_WORDS + ROWS) * PC + ROWS * N_WORDS;   // 256
    float* x2 = c2 + N_WORDS;                                    // 32

    const int tid  = threadIdx.x;
    const int book = blockIdx.x & 7;
    const int n0   = (blockIdx.x >> 3) * ROWS;
    const int cbase = book * L_WORD;

    // ---- stage Cb: 256 x 64 (16 float4 per thread) ----
    #pragma unroll
    for (int i = 0; i < 16; ++i) {
        const int s  = tid + 256 * i;      // 0..4095
        const int m  = s >> 4;
        const int l4 = (s & 15) << 2;
        const float4 v = *reinterpret_cast<const float4*>(&C[(size_t)m * D_OUT + cbase + l4]);
        *reinterpret_cast<float4*>(&Cb[m][l4]) = v;
    }
    // ---- stage Xs: 32 x 64 (2 float4 per thread) ----
    #pragma unroll
    for (int i = 0; i < 2; ++i) {
        const int s  = tid + 256 * i;      // 0..511
        const int r  = s >> 4;
        const int l4 = (s & 15) << 2;
        const float4 v = *reinterpret_cast<const float4*>(&X[(size_t)(n0 + r) * D_OUT + cbase + l4]);
        *reinterpret_cast<float4*>(&Xs[r][l4]) = v;
    }
    __syncthreads();

    // ---- norms ----
    {
        float s = 0.f;
        #pragma unroll
        for (int l = 0; l < L_WORD; l += 4) {
            const float4 c = *reinterpret_cast<const float4*>(&Cb[tid][l]);
            s = fmaf(c.x, c.x, s); s = fmaf(c.y, c.y, s);
            s = fmaf(c.z, c.z, s); s = fmaf(c.w, c.w, s);
        }
        c2[tid] = s;
    }
    if (tid < ROWS) {
        float s = 0.f;
        #pragma unroll
        for (int l = 0; l < L_WORD; l += 4) {
            const float4 c = *reinterpret_cast<const float4*>(&Xs[tid][l]);
            s = fmaf(c.x, c.x, s); s = fmaf(c.y, c.y, s);
            s = fmaf(c.z, c.z, s); s = fmaf(c.w, c.w, s);
        }
        x2[tid] = s;
    }
    __syncthreads();

    // ---- distances: each thread does a 4-row x 4-codeword register tile ----
    const int mg = tid & 63;   // codeword group: m = mg + 64*j
    const int g  = tid >> 6;   // wave id 0..3
    #pragma unroll
    for (int rp = 0; rp < 2; ++rp) {
        const int rbase = (g + rp * 4) * 4;   // 0,4,...,28
        float dot[4][4] = {};
        for (int l = 0; l < L_WORD; l += 4) {
            float4 xv[4];
            #pragma unroll
            for (int i = 0; i < 4; ++i)
                xv[i] = *reinterpret_cast<const float4*>(&Xs[rbase + i][l]);
            #pragma unroll
            for (int j = 0; j < 4; ++j) {
                const float4 cv = *reinterpret_cast<const float4*>(&Cb[mg + 64 * j][l]);
                #pragma unroll
                for (int i = 0; i < 4; ++i) {
                    dot[i][j] = fmaf(xv[i].x, cv.x, dot[i][j]);
                    dot[i][j] = fmaf(xv[i].y, cv.y, dot[i][j]);
                    dot[i][j] = fmaf(xv[i].z, cv.z, dot[i][j]);
                    dot[i][j] = fmaf(xv[i].w, cv.w, dot[i][j]);
                }
            }
        }
        #pragma unroll
        for (int j = 0; j < 4; ++j) {
            const int m = mg + 64 * j;
            const float cc = c2[m];
            #pragma unroll
            for (int i = 0; i < 4; ++i)
                dist[rbase + i][m] = x2[rbase + i] + cc - 2.f * dot[i][j];
        }
    }
    __syncthreads();

    // ---- softmax over codewords (wave-parallel, 8 rows per wave) ----
    const int lane = tid & 63;
    #pragma unroll
    for (int i = 0; i < 8; ++i) {
        const int r = g * 8 + i;
        float d0 = dist[r][lane];
        float d1 = dist[r][lane + 64];
        float d2 = dist[r][lane + 128];
        float d3 = dist[r][lane + 192];
        float mn = fminf(fminf(d0, d1), fminf(d2, d3));
        #pragma unroll
        for (int off = 32; off > 0; off >>= 1)
            mn = fminf(mn, __shfl_xor(mn, off, 64));
        const float p0 = expf(-TAU * (d0 - mn));
        const float p1 = expf(-TAU * (d1 - mn));
        const float p2 = expf(-TAU * (d2 - mn));
        const float p3 = expf(-TAU * (d3 - mn));
        float s = p0 + p1 + p2 + p3;
        #pragma unroll
        for (int off = 32; off > 0; off >>= 1)
            s += __shfl_xor(s, off, 64);
        const float inv = 1.0f / s;
        dist[r][lane]       = p0 * inv;
        dist[r][lane + 64]  = p1 * inv;
        dist[r][lane + 128] = p2 * inv;
        dist[r][lane + 192] = p3 * inv;
    }
    __syncthreads();

    // ---- Z = soft @ Cb : each thread accumulates 2 rows x float4 of l ----
    const int lg = tid & 15;
    const int rs = tid >> 4;           // 0..15
    const int l0 = lg << 2;
    float4 z0 = {0.f, 0.f, 0.f, 0.f}, z1 = {0.f, 0.f, 0.f, 0.f};
    #pragma unroll 4
    for (int m = 0; m < N_WORDS; ++m) {
        const float w0 = dist[rs][m];
        const float w1 = dist[rs + 16][m];
        const float4 cv = *reinterpret_cast<const float4*>(&Cb[m][l0]);
        z0.x = fmaf(w0, cv.x, z0.x); z0.y = fmaf(w0, cv.y, z0.y);
        z0.z = fmaf(w0, cv.z, z0.z); z0.w = fmaf(w0, cv.w, z0.w);
        z1.x = fmaf(w1, cv.x, z1.x); z1.y = fmaf(w1, cv.y, z1.y);
        z1.z = fmaf(w1, cv.z, z1.z); z1.w = fmaf(w1, cv.w, z1.w);
    }
    *reinterpret_cast<float4*>(&Z[(size_t)(n0 + rs) * D_OUT + cbase + l0])      = z0;
    *reinterpret_cast<float4*>(&Z[(size_t)(n0 + rs + 16) * D_OUT + cbase + l0]) = z1;
}

// ---------------- launch ----------------
extern "C" void kernel_launch(void* const* d_in, const int* in_sizes, int n_in,
                              void* d_out, int out_size, void* d_ws, size_t ws_size,
                              hipStream_t stream) {
    const float* x = (const float*)d_in[0];
    const float* W = (const float*)d_in[1];
    const float* b = (const float*)d_in[2];
    const float* C = (const float*)d_in[3];

    float* X = (float*)d_out;                       // output 0: [65536, 512]
    float* Z = X + (size_t)N_ROWS * D_OUT;          // output 1: [65536, 512]

    // Kernel 1: fc
    gemm_fc<<<dim3((N_ROWS / BM) * (D_OUT / BN)), dim3(256), 0, stream>>>(x, W, b, X);

    // Kernel 2: quantization head (reads X from d_out, writes Z)
    const size_t lds_bytes = ((size_t)(N_WORDS + ROWS) * PC + ROWS * N_WORDS + N_WORDS + ROWS) * sizeof(float);
    quant_head<<<dim3(N_BOOKS * (N_ROWS / ROWS)), dim3(256), lds_bytes, stream>>>(X, C, Z);
}

// Round 2
// 319.619 us; speedup vs baseline: 4.8895x; 4.8895x over previous
//
#include <hip/hip_runtime.h>
#include <cstdint>
#include <cstddef>

#define N_ROWS   65536
#define D_IN     512
#define D_OUT    512
#define N_WORDS  256
#define N_BOOKS  8
#define L_WORD   64
#define TAU      5.0f

typedef __attribute__((ext_vector_type(8))) short short8;
typedef __attribute__((ext_vector_type(4))) float f32x4;

__device__ __forceinline__ unsigned short f2bf(float f) {
    unsigned u = __builtin_bit_cast(unsigned, f);
    u += 0x7fffu + ((u >> 16) & 1u);           // round-to-nearest-even
    return (unsigned short)(u >> 16);
}
__device__ __forceinline__ float bf2f(unsigned short h) {
    unsigned u = ((unsigned)h) << 16;
    return __builtin_bit_cast(float, u);
}

// ============ Kernel 0: pre-pack codebook into MFMA fragment order ============
// packA [b][ks(2)][n(16)][lane(64)][i(8)]  : B-frag for xc GEMM (B[k][m]=Cb[m][k])
//   lane l, elem i -> Cb[(l&15)+16n][(l>>4)*8+i+32ks]
// packB [b][ks2(8)][n2(4)][lane(64)][i(8)] : B-frag for Z GEMM  (B[m][l]=Cb[m][l])
//   lane l, elem i -> Cb[(l>>4)*8+i+32ks2][(l&15)+16n2]
// c2   [b][m] = sum_l bf16(Cb[m][l])^2   (fp32)
__global__ __launch_bounds__(256) void prep_codebook(
        const float* __restrict__ C, unsigned short* __restrict__ packA,
        unsigned short* __restrict__ packB, float* __restrict__ c2) {
    const int gid = blockIdx.x * 256 + threadIdx.x;
    if (gid < 131072) {                       // packA
        const int i  = gid & 7;
        const int l  = (gid >> 3) & 63;
        const int n  = (gid >> 9) & 15;
        const int ks = (gid >> 13) & 1;
        const int b  = gid >> 14;
        const int row = (l & 15) + 16 * n;                    // m
        const int col = b * 64 + (l >> 4) * 8 + i + 32 * ks;  // k within C row
        packA[gid] = f2bf(C[(size_t)row * D_IN + col]);
    } else if (gid < 262144) {                // packB
        const int g   = gid - 131072;
        const int i   = g & 7;
        const int l   = (g >> 3) & 63;
        const int n2  = (g >> 9) & 3;
        const int ks2 = (g >> 11) & 7;
        const int b   = g >> 14;
        const int m   = (l >> 4) * 8 + i + 32 * ks2;
        const int col = b * 64 + (l & 15) + 16 * n2;
        packB[g] = f2bf(C[(size_t)m * D_IN + col]);
    } else if (gid < 264192) {                // c2
        const int t = gid - 262144;
        const int b = t >> 8, m = t & 255;
        const float* cp = C + (size_t)m * D_IN + b * 64;
        float s = 0.f;
        for (int l = 0; l < L_WORD; ++l) {
            const float v = bf2f(f2bf(cp[l]));
            s = fmaf(v, v, s);
        }
        c2[t] = s;
    }
}

// ============ Kernel 1: X = x @ W^T + b  (bf16 MFMA, fp32 accum) ============
#define ASTR 40   // padded LDS row stride in bf16 elems (80 B: 2-way banks = free)

__global__ __launch_bounds__(256) void gemm_fc(
        const float* __restrict__ x, const float* __restrict__ W,
        const float* __restrict__ bias, float* __restrict__ X) {
    __shared__ unsigned short Asm[128 * ASTR];
    __shared__ unsigned short Bsm[128 * ASTR];

    const int tid = threadIdx.x;
    const int bid = blockIdx.x;
    const int swz = (bid & 7) * 256 + (bid >> 3);   // XCD swizzle (2048/8=256)
    const int bm = swz >> 2, bn = swz & 3;
    const int n0 = bm * 128, c0 = bn * 128;
    const int lane = tid & 63, w = tid >> 6;
    const int wr = w >> 1, wc = w & 1;
    const int lo = lane & 15, hi = lane >> 4;

    f32x4 acc[4][4];
    #pragma unroll
    for (int i = 0; i < 4; ++i)
        #pragma unroll
        for (int j = 0; j < 4; ++j) acc[i][j] = (f32x4){0.f, 0.f, 0.f, 0.f};

    for (int k0 = 0; k0 < D_IN; k0 += 32) {
        #pragma unroll
        for (int it = 0; it < 4; ++it) {
            const int idx = tid + 256 * it;          // 0..1023
            const int r = idx >> 3, f = idx & 7;
            const float4 va = *reinterpret_cast<const float4*>(
                &x[(size_t)(n0 + r) * D_IN + k0 + f * 4]);
            ushort4 pa;
            pa.x = f2bf(va.x); pa.y = f2bf(va.y); pa.z = f2bf(va.z); pa.w = f2bf(va.w);
            *reinterpret_cast<ushort4*>(&Asm[r * ASTR + f * 4]) = pa;
            const float4 vb = *reinterpret_cast<const float4*>(
                &W[(size_t)(c0 + r) * D_IN + k0 + f * 4]);
            ushort4 pb;
            pb.x = f2bf(vb.x); pb.y = f2bf(vb.y); pb.z = f2bf(vb.z); pb.w = f2bf(vb.w);
            *reinterpret_cast<ushort4*>(&Bsm[r * ASTR + f * 4]) = pb;
        }
        __syncthreads();
        short8 a[4], bb[4];
        #pragma unroll
        for (int fm = 0; fm < 4; ++fm)
            a[fm] = *reinterpret_cast<const short8*>(&Asm[(wr * 64 + fm * 16 + lo) * ASTR + hi * 8]);
        #pragma unroll
        for (int fn = 0; fn < 4; ++fn)
            bb[fn] = *reinterpret_cast<const short8*>(&Bsm[(wc * 64 + fn * 16 + lo) * ASTR + hi * 8]);
        #pragma unroll
        for (int fm = 0; fm < 4; ++fm)
            #pragma unroll
            for (int fn = 0; fn < 4; ++fn)
                acc[fm][fn] = __builtin_amdgcn_mfma_f32_16x16x32_bf16(
                    a[fm], bb[fn], acc[fm][fn], 0, 0, 0);
        __syncthreads();
    }

    #pragma unroll
    for (int fn = 0; fn < 4; ++fn) {
        const float bv = bias[c0 + wc * 64 + fn * 16 + lo];
        #pragma unroll
        for (int fm = 0; fm < 4; ++fm)
            #pragma unroll
            for (int j = 0; j < 4; ++j)
                X[(size_t)(n0 + wr * 64 + fm * 16 + hi * 4 + j) * D_OUT
                  + c0 + wc * 64 + fn * 16 + lo] = acc[fm][fn][j] + bv;
    }
}

// ============ Kernel 2: soft quantization head (MFMA) ============
// Block = (book b, 64 rows). 4 waves.
// Phase A: xc = Xb·Cb^T  — wave w owns codeword frags n=4w..4w+3 (64 of 256 m's).
// Softmax in fp32 in the accumulators; cross-wave max/sum via pmax/psum LDS.
// soft -> bf16 in LDS [64][264]. Phase B: Z = soft·Cb — wave w owns l-frag w.
#define SSTR 264   // soft LDS row stride (528 B: bank-floor b128 reads)

__global__ __launch_bounds__(256) void quant_head(
        const float* __restrict__ X, const unsigned short* __restrict__ packA,
        const unsigned short* __restrict__ packB, const float* __restrict__ c2g,
        float* __restrict__ Z) {
    __shared__ unsigned short soft[64 * SSTR];
    __shared__ float pmax[4][64];
    __shared__ float psum[4][64];
    __shared__ float c2s[256];

    const int tid  = threadIdx.x;
    const int b    = blockIdx.x & 7;
    const int n0   = (blockIdx.x >> 3) * 64;
    const int lane = tid & 63;
    const int w    = tid >> 6;
    const int lo = lane & 15, hi = lane >> 4;

    c2s[tid] = c2g[b * 256 + tid];

    // ---- X rows -> bf16 A-frags (direct global, 128B-chunk coalesced) + row norms ----
    short8 af[4][2];
    float x2p[4];
    #pragma unroll
    for (int rf = 0; rf < 4; ++rf) {
        const float* xp = X + (size_t)(n0 + rf * 16 + lo) * D_OUT + b * 64 + hi * 8;
        float s = 0.f;
        #pragma unroll
        for (int ks = 0; ks < 2; ++ks) {
            const float4 v0 = *reinterpret_cast<const float4*>(xp + ks * 32);
            const float4 v1 = *reinterpret_cast<const float4*>(xp + ks * 32 + 4);
            unsigned short c[8];
            c[0] = f2bf(v0.x); c[1] = f2bf(v0.y); c[2] = f2bf(v0.z); c[3] = f2bf(v0.w);
            c[4] = f2bf(v1.x); c[5] = f2bf(v1.y); c[6] = f2bf(v1.z); c[7] = f2bf(v1.w);
            short8 t;
            #pragma unroll
            for (int i = 0; i < 8; ++i) {
                t[i] = (short)c[i];
                const float fv = bf2f(c[i]);
                s = fmaf(fv, fv, s);
            }
            af[rf][ks] = t;
        }
        s += __shfl_xor(s, 16, 64);
        s += __shfl_xor(s, 32, 64);
        x2p[rf] = s;   // full ||row||^2, row = rf*16 + lo
    }

    // ---- xc MFMA ----
    f32x4 acc[4][4];
    #pragma unroll
    for (int rf = 0; rf < 4; ++rf)
        #pragma unroll
        for (int nf = 0; nf < 4; ++nf) acc[rf][nf] = (f32x4){0.f, 0.f, 0.f, 0.f};

    #pragma unroll
    for (int ks = 0; ks < 2; ++ks) {
        #pragma unroll
        for (int nf = 0; nf < 4; ++nf) {
            const short8 bfr = *reinterpret_cast<const short8*>(
                packA + ((size_t)(((b * 2 + ks) * 16) + (4 * w + nf)) * 64 + lane) * 8);
            #pragma unroll
            for (int rf = 0; rf < 4; ++rf)
                acc[rf][nf] = __builtin_amdgcn_mfma_f32_16x16x32_bf16(
                    af[rf][ks], bfr, acc[rf][nf], 0, 0, 0);
        }
    }

    __syncthreads();   // c2s ready

    // ---- logits = -TAU * (x2 + c2 - 2 xc), in place in acc ----
    #pragma unroll
    for (int rf = 0; rf < 4; ++rf) {
        #pragma unroll
        for (int j = 0; j < 4; ++j) {
            const float x2v = __shfl(x2p[rf], hi * 4 + j, 64);
            #pragma unroll
            for (int nf = 0; nf < 4; ++nf) {
                const float d = x2v + c2s[(4 * w + nf) * 16 + lo] - 2.f * acc[rf][nf][j];
                acc[rf][nf][j] = -TAU * d;
            }
        }
    }
    // wave-partial row max over this wave's 64 m's
    #pragma unroll
    for (int rf = 0; rf < 4; ++rf) {
        #pragma unroll
        for (int j = 0; j < 4; ++j) {
            float mx = fmaxf(fmaxf(acc[rf][0][j], acc[rf][1][j]),
                             fmaxf(acc[rf][2][j], acc[rf][3][j]));
            mx = fmaxf(mx, __shfl_xor(mx, 1, 64));
            mx = fmaxf(mx, __shfl_xor(mx, 2, 64));
            mx = fmaxf(mx, __shfl_xor(mx, 4, 64));
            mx = fmaxf(mx, __shfl_xor(mx, 8, 64));
            if (lo == 0) pmax[w][rf * 16 + hi * 4 + j] = mx;
        }
    }
    __syncthreads();
    // exp with global max, partial sums
    #pragma unroll
    for (int rf = 0; rf < 4; ++rf) {
        #pragma unroll
        for (int j = 0; j < 4; ++j) {
            const int r = rf * 16 + hi * 4 + j;
            const float mg = fmaxf(fmaxf(pmax[0][r], pmax[1][r]),
                                   fmaxf(pmax[2][r], pmax[3][r]));
            float s = 0.f;
            #pragma unroll
            for (int nf = 0; nf < 4; ++nf) {
                const float p = __expf(acc[rf][nf][j] - mg);
                acc[rf][nf][j] = p;
                s += p;
            }
            s += __shfl_xor(s, 1, 64);
            s += __shfl_xor(s, 2, 64);
            s += __shfl_xor(s, 4, 64);
            s += __shfl_xor(s, 8, 64);
            if (lo == 0) psum[w][r] = s;
        }
    }
    __syncthreads();
    // normalize -> bf16 -> soft LDS
    #pragma unroll
    for (int rf = 0; rf < 4; ++rf) {
        #pragma unroll
        for (int j = 0; j < 4; ++j) {
            const int r = rf * 16 + hi * 4 + j;
            const float inv = 1.f / (psum[0][r] + psum[1][r] + psum[2][r] + psum[3][r]);
            #pragma unroll
            for (int nf = 0; nf < 4; ++nf)
                soft[r * SSTR + (4 * w + nf) * 16 + lo] = f2bf(acc[rf][nf][j] * inv);
        }
    }
    __syncthreads();

    // ---- Z = soft @ Cb : wave w owns output cols w*16..w*16+15 ----
    f32x4 acc2[4];
    #pragma unroll
    for (int rf = 0; rf < 4; ++rf) acc2[rf] = (f32x4){0.f, 0.f, 0.f, 0.f};
    #pragma unroll
    for (int ks2 = 0; ks2 < 8; ++ks2) {
        const short8 bv = *reinterpret_cast<const short8*>(
            packB + ((size_t)(((b * 8 + ks2) * 4) + w) * 64 + lane) * 8);
        #pragma unroll
        for (int rf = 0; rf < 4; ++rf) {
            const short8 pa = *reinterpret_cast<const short8*>(
                &soft[(rf * 16 + lo) * SSTR + ks2 * 32 + hi * 8]);
            acc2[rf] = __builtin_amdgcn_mfma_f32_16x16x32_bf16(pa, bv, acc2[rf], 0, 0, 0);
        }
    }
    #pragma unroll
    for (int rf = 0; rf < 4; ++rf)
        #pragma unroll
        for (int j = 0; j < 4; ++j)
            Z[(size_t)(n0 + rf * 16 + hi * 4 + j) * D_OUT + b * 64 + w * 16 + lo] = acc2[rf][j];
}

// ============ launch ============
extern "C" void kernel_launch(void* const* d_in, const int* in_sizes, int n_in,
                              void* d_out, int out_size, void* d_ws, size_t ws_size,
                              hipStream_t stream) {
    const float* x = (const float*)d_in[0];
    const float* W = (const float*)d_in[1];
    const float* b = (const float*)d_in[2];
    const float* C = (const float*)d_in[3];

    float* X = (float*)d_out;                      // output 0: [65536, 512]
    float* Z = X + (size_t)N_ROWS * D_OUT;         // output 1: [65536, 512]

    unsigned short* packA = (unsigned short*)d_ws;          // 131072 bf16 = 256 KB
    unsigned short* packB = packA + 131072;                 // 131072 bf16 = 256 KB
    float*          c2g   = (float*)(packB + 131072);       // 2048 fp32  =   8 KB

    prep_codebook<<<dim3(1032), dim3(256), 0, stream>>>(C, packA, packB, c2g);
    gemm_fc<<<dim3(2048), dim3(256), 0, stream>>>(x, W, b, X);
    quant_head<<<dim3(N_BOOKS * (N_ROWS / 64)), dim3(256), 0, stream>>>(X, packA, packB, c2g, Z);
}

// Round 3
// 241.929 us; speedup vs baseline: 6.4597x; 1.3211x over previous
//
#include <hip/hip_runtime.h>
#include <cstdint>
#include <cstddef>

#define N_ROWS   65536
#define D_IN     512
#define D_OUT    512
#define N_WORDS  256
#define N_BOOKS  8
#define TAU      5.0f
#define LOG2E    1.44269504088896340736f

typedef __attribute__((ext_vector_type(8))) short short8;
typedef __attribute__((ext_vector_type(4))) float f32x4;

// hardware bf16 convert (RNE) — native __bf16 lets the compiler pair into v_cvt_pk_bf16_f32
__device__ __forceinline__ unsigned short f2bf(float f) {
    __bf16 h = (__bf16)f;
    return __builtin_bit_cast(unsigned short, h);
}
__device__ __forceinline__ float bf2f(unsigned short h) {
    unsigned u = ((unsigned)h) << 16;
    return __builtin_bit_cast(float, u);
}

// ============ Kernel 0: pre-pack codebook into MFMA fragment order ============
// packA [b][ks(2)][mf(16)][lane(64)][i(8)] : Cb fragment, works as A (row=m) or B (col=m)
//   lane l, elem i -> Cb[(l&15)+16*mf][(l>>4)*8+i+32*ks]
// packB [b][ks2(8)][n2(4)][lane(64)][i(8)] : B-frag for Z GEMM (B[m][l]=Cb[m][l])
//   lane l, elem i -> Cb[(l>>4)*8+i+32*ks2][(l&15)+16*n2]
// nc2  [b][m] = -TAU*LOG2E * sum_l bf16(Cb[m][l])^2   (log2-domain bias)
__global__ __launch_bounds__(256) void prep_codebook(
        const float* __restrict__ C, unsigned short* __restrict__ packA,
        unsigned short* __restrict__ packB, float* __restrict__ nc2) {
    const int gid = blockIdx.x * 256 + threadIdx.x;
    if (gid < 131072) {                       // packA
        const int i  = gid & 7;
        const int l  = (gid >> 3) & 63;
        const int mf = (gid >> 9) & 15;
        const int ks = (gid >> 13) & 1;
        const int b  = gid >> 14;
        const int row = (l & 15) + 16 * mf;                   // m
        const int col = b * 64 + (l >> 4) * 8 + i + 32 * ks;  // k within C row
        packA[gid] = f2bf(C[(size_t)row * D_IN + col]);
    } else if (gid < 262144) {                // packB
        const int g   = gid - 131072;
        const int i   = g & 7;
        const int l   = (g >> 3) & 63;
        const int n2  = (g >> 9) & 3;
        const int ks2 = (g >> 11) & 7;
        const int b   = g >> 14;
        const int m   = (l >> 4) * 8 + i + 32 * ks2;
        const int col = b * 64 + (l & 15) + 16 * n2;
        packB[g] = f2bf(C[(size_t)m * D_IN + col]);
    } else if (gid < 264192) {                // nc2
        const int t = gid - 262144;
        const int b = t >> 8, m = t & 255;
        const float* cp = C + (size_t)m * D_IN + b * 64;
        float s = 0.f;
        for (int l = 0; l < 64; ++l) {
            const float v = bf2f(f2bf(cp[l]));
            s = fmaf(v, v, s);
        }
        nc2[t] = -TAU * LOG2E * s;
    }
}

// ============ Kernel 1: X = x @ W^T + b  (bf16 MFMA, fp32 accum) ============
#define ASTR 40   // padded LDS row stride in bf16 elems (80 B: 2-way banks = free)

__global__ __launch_bounds__(256) void gemm_fc(
        const float* __restrict__ x, const float* __restrict__ W,
        const float* __restrict__ bias, float* __restrict__ X) {
    __shared__ unsigned short Asm[128 * ASTR];
    __shared__ unsigned short Bsm[128 * ASTR];

    const int tid = threadIdx.x;
    const int bid = blockIdx.x;
    const int swz = (bid & 7) * 256 + (bid >> 3);   // XCD swizzle (2048 % 8 == 0)
    const int bm = swz >> 2, bn = swz & 3;
    const int n0 = bm * 128, c0 = bn * 128;
    const int lane = tid & 63, w = tid >> 6;
    const int wr = w >> 1, wc = w & 1;
    const int lo = lane & 15, hi = lane >> 4;

    const int sr = tid >> 1;            // staging row 0..127 (2 threads/row)
    const int sf = (tid & 1) << 4;      // k-offset 0 or 16

    f32x4 acc[4][4];
    #pragma unroll
    for (int i = 0; i < 4; ++i)
        #pragma unroll
        for (int j = 0; j < 4; ++j) acc[i][j] = (f32x4){0.f, 0.f, 0.f, 0.f};

    // register double-buffer of the staging loads: each thread owns 16 k-elems
    // of one row of A and of B per K-step (4 float4 each).
    float4 ra[4], rb[4];
    {
        const float* xa = &x[(size_t)(n0 + sr) * D_IN + sf];
        const float* wb = &W[(size_t)(c0 + sr) * D_IN + sf];
        #pragma unroll
        for (int q = 0; q < 4; ++q) {
            ra[q] = *reinterpret_cast<const float4*>(xa + q * 4);
            rb[q] = *reinterpret_cast<const float4*>(wb + q * 4);
        }
    }

    for (int k0 = 0; k0 < D_IN; k0 += 32) {
        // convert + write current tile to LDS
        #pragma unroll
        for (int q = 0; q < 4; ++q) {
            ushort4 pa, pb;
            pa.x = f2bf(ra[q].x); pa.y = f2bf(ra[q].y);
            pa.z = f2bf(ra[q].z); pa.w = f2bf(ra[q].w);
            pb.x = f2bf(rb[q].x); pb.y = f2bf(rb[q].y);
            pb.z = f2bf(rb[q].z); pb.w = f2bf(rb[q].w);
            *reinterpret_cast<ushort4*>(&Asm[sr * ASTR + sf + q * 4]) = pa;
            *reinterpret_cast<ushort4*>(&Bsm[sr * ASTR + sf + q * 4]) = pb;
        }
        // issue next tile's loads (latency hides under this tile's MFMAs)
        if (k0 + 32 < D_IN) {
            const float* xa = &x[(size_t)(n0 + sr) * D_IN + k0 + 32 + sf];
            const float* wb = &W[(size_t)(c0 + sr) * D_IN + k0 + 32 + sf];
            #pragma unroll
            for (int q = 0; q < 4; ++q) {
                ra[q] = *reinterpret_cast<const float4*>(xa + q * 4);
                rb[q] = *reinterpret_cast<const float4*>(wb + q * 4);
            }
        }
        __syncthreads();
        short8 a[4], bb[4];
        #pragma unroll
        for (int fm = 0; fm < 4; ++fm)
            a[fm] = *reinterpret_cast<const short8*>(&Asm[(wr * 64 + fm * 16 + lo) * ASTR + hi * 8]);
        #pragma unroll
        for (int fn = 0; fn < 4; ++fn)
            bb[fn] = *reinterpret_cast<const short8*>(&Bsm[(wc * 64 + fn * 16 + lo) * ASTR + hi * 8]);
        #pragma unroll
        for (int fm = 0; fm < 4; ++fm)
            #pragma unroll
            for (int fn = 0; fn < 4; ++fn)
                acc[fm][fn] = __builtin_amdgcn_mfma_f32_16x16x32_bf16(
                    a[fm], bb[fn], acc[fm][fn], 0, 0, 0);
        __syncthreads();
    }

    #pragma unroll
    for (int fn = 0; fn < 4; ++fn) {
        const float bv = bias[c0 + wc * 64 + fn * 16 + lo];
        #pragma unroll
        for (int fm = 0; fm < 4; ++fm)
            #pragma unroll
            for (int j = 0; j < 4; ++j)
                X[(size_t)(n0 + wr * 64 + fm * 16 + hi * 4 + j) * D_OUT
                  + c0 + wc * 64 + fn * 16 + lo] = acc[fm][fn][j] + bv;
    }
}

// ============ Kernel 2: soft quantization head (swapped-operand MFMA) ============
// Block = (book b, 64 rows). 4 waves; wave w owns m-frags 4w..4w+3 (64 of 256 m's).
// xc = mfma(Cb, X^T): D-col = x-row, D-row = m  ->  softmax's m-reduce is
// 16 in-lane values + 2 shuffles (xor16/32) + cross-wave LDS.
// Unnormalized p -> bf16 soft LDS; 1/sum folded into the Z store.
#define SSTR 264   // soft LDS row stride in bf16 elems

__global__ __launch_bounds__(256) void quant_head(
        const float* __restrict__ X, const unsigned short* __restrict__ packA,
        const unsigned short* __restrict__ packB, const float* __restrict__ nc2g,
        float* __restrict__ Z) {
    __shared__ __attribute__((aligned(16))) unsigned short soft[64 * SSTR];
    __shared__ float pmax[4][64];
    __shared__ float psum[4][64];
    __shared__ float invs[64];
    __shared__ float nc2s[256];

    const int tid  = threadIdx.x;
    const int b    = blockIdx.x & 7;
    const int n0   = (blockIdx.x >> 3) * 64;
    const int lane = tid & 63;
    const int w    = tid >> 6;
    const int lo = lane & 15, hi = lane >> 4;

    nc2s[tid] = nc2g[b * 256 + tid];

    // ---- X rows -> bf16 fragments (used as MFMA B-operand: col=x-row, k=feature) ----
    short8 xf[4][2];
    #pragma unroll
    for (int rf = 0; rf < 4; ++rf) {
        const float* xp = X + (size_t)(n0 + rf * 16 + lo) * D_OUT + b * 64 + hi * 8;
        #pragma unroll
        for (int ks = 0; ks < 2; ++ks) {
            const float4 v0 = *reinterpret_cast<const float4*>(xp + ks * 32);
            const float4 v1 = *reinterpret_cast<const float4*>(xp + ks * 32 + 4);
            short8 t;
            t[0] = (short)f2bf(v0.x); t[1] = (short)f2bf(v0.y);
            t[2] = (short)f2bf(v0.z); t[3] = (short)f2bf(v0.w);
            t[4] = (short)f2bf(v1.x); t[5] = (short)f2bf(v1.y);
            t[6] = (short)f2bf(v1.z); t[7] = (short)f2bf(v1.w);
            xf[rf][ks] = t;
        }
    }

    // ---- xc MFMA (swapped: Cb is the A operand) ----
    f32x4 acc[4][4];   // [mf][rf]
    #pragma unroll
    for (int mf = 0; mf < 4; ++mf)
        #pragma unroll
        for (int rf = 0; rf < 4; ++rf) acc[mf][rf] = (f32x4){0.f, 0.f, 0.f, 0.f};

    #pragma unroll
    for (int ks = 0; ks < 2; ++ks) {
        #pragma unroll
        for (int mf = 0; mf < 4; ++mf) {
            const short8 cfr = *reinterpret_cast<const short8*>(
                packA + ((size_t)(((b * 2 + ks) * 16) + (4 * w + mf)) * 64 + lane) * 8);
            #pragma unroll
            for (int rf = 0; rf < 4; ++rf)
                acc[mf][rf] = __builtin_amdgcn_mfma_f32_16x16x32_bf16(
                    cfr, xf[rf][ks], acc[mf][rf], 0, 0, 0);
        }
    }

    __syncthreads();   // nc2s ready

    // ---- logits (log2 domain): l = (2*TAU*LOG2E)*xc + nc2[m]   (x^2 cancels in softmax)
    const float S2 = 2.0f * TAU * LOG2E;
    #pragma unroll
    for (int mf = 0; mf < 4; ++mf) {
        const f32x4 nv = *reinterpret_cast<const f32x4*>(&nc2s[(4 * w + mf) * 16 + hi * 4]);
        #pragma unroll
        for (int rf = 0; rf < 4; ++rf)
            #pragma unroll
            for (int j = 0; j < 4; ++j)
                acc[mf][rf][j] = fmaf(acc[mf][rf][j], S2, nv[j]);
    }

    // ---- per-row max over this wave's 64 m's (16 in-lane + 2 shuffles) ----
    #pragma unroll
    for (int rf = 0; rf < 4; ++rf) {
        float mx = acc[0][rf][0];
        #pragma unroll
        for (int mf = 0; mf < 4; ++mf)
            #pragma unroll
            for (int j = 0; j < 4; ++j) mx = fmaxf(mx, acc[mf][rf][j]);
        mx = fmaxf(mx, __shfl_xor(mx, 16, 64));
        mx = fmaxf(mx, __shfl_xor(mx, 32, 64));
        if (hi == 0) pmax[w][rf * 16 + lo] = mx;
    }
    __syncthreads();

    // ---- exp2, in-lane sums, unnormalized bf16 p -> soft ----
    #pragma unroll
    for (int rf = 0; rf < 4; ++rf) {
        const int r = rf * 16 + lo;
        const float mg = fmaxf(fmaxf(pmax[0][r], pmax[1][r]),
                               fmaxf(pmax[2][r], pmax[3][r]));
        float s = 0.f;
        #pragma unroll
        for (int mf = 0; mf < 4; ++mf) {
            ushort4 us;
            float p0 = exp2f(acc[mf][rf][0] - mg);
            float p1 = exp2f(acc[mf][rf][1] - mg);
            float p2 = exp2f(acc[mf][rf][2] - mg);
            float p3 = exp2f(acc[mf][rf][3] - mg);
            s += (p0 + p1) + (p2 + p3);
            us.x = f2bf(p0); us.y = f2bf(p1); us.z = f2bf(p2); us.w = f2bf(p3);
            *reinterpret_cast<ushort4*>(
                &soft[r * SSTR + (4 * w + mf) * 16 + hi * 4]) = us;
        }
        s += __shfl_xor(s, 16, 64);
        s += __shfl_xor(s, 32, 64);
        if (hi == 0) psum[w][r] = s;
    }
    __syncthreads();

    if (tid < 64)
        invs[tid] = 1.0f / (psum[0][tid] + psum[1][tid] + psum[2][tid] + psum[3][tid]);
    __syncthreads();

    // ---- Z = soft @ Cb : wave w owns output cols w*16..w*16+15 ----
    f32x4 acc2[4];
    #pragma unroll
    for (int rf = 0; rf < 4; ++rf) acc2[rf] = (f32x4){0.f, 0.f, 0.f, 0.f};
    #pragma unroll
    for (int ks2 = 0; ks2 < 8; ++ks2) {
        const short8 bv = *reinterpret_cast<const short8*>(
            packB + ((size_t)(((b * 8 + ks2) * 4) + w) * 64 + lane) * 8);
        #pragma unroll
        for (int rf = 0; rf < 4; ++rf) {
            const short8 pa = *reinterpret_cast<const short8*>(
                &soft[(rf * 16 + lo) * SSTR + ks2 * 32 + hi * 8]);
            acc2[rf] = __builtin_amdgcn_mfma_f32_16x16x32_bf16(pa, bv, acc2[rf], 0, 0, 0);
        }
    }
    #pragma unroll
    for (int rf = 0; rf < 4; ++rf) {
        const f32x4 iv = *reinterpret_cast<const f32x4*>(&invs[rf * 16 + hi * 4]);
        #pragma unroll
        for (int j = 0; j < 4; ++j)
            Z[(size_t)(n0 + rf * 16 + hi * 4 + j) * D_OUT + b * 64 + w * 16 + lo]
                = acc2[rf][j] * iv[j];
    }
}

// ============ launch ============
extern "C" void kernel_launch(void* const* d_in, const int* in_sizes, int n_in,
                              void* d_out, int out_size, void* d_ws, size_t ws_size,
                              hipStream_t stream) {
    const float* x = (const float*)d_in[0];
    const float* W = (const float*)d_in[1];
    const float* b = (const float*)d_in[2];
    const float* C = (const float*)d_in[3];

    float* X = (float*)d_out;                      // output 0: [65536, 512]
    float* Z = X + (size_t)N_ROWS * D_OUT;         // output 1: [65536, 512]

    unsigned short* packA = (unsigned short*)d_ws;          // 131072 bf16 = 256 KB
    unsigned short* packB = packA + 131072;                 // 131072 bf16 = 256 KB
    float*          nc2g  = (float*)(packB + 131072);       // 2048 fp32  =   8 KB

    prep_codebook<<<dim3(1032), dim3(256), 0, stream>>>(C, packA, packB, nc2g);
    gemm_fc<<<dim3(2048), dim3(256), 0, stream>>>(x, W, b, X);
    quant_head<<<dim3(N_BOOKS * (N_ROWS / 64)), dim3(256), 0, stream>>>(X, packA, packB, nc2g, Z);
}